// Round 9
// baseline (309.446 us; speedup 1.0000x reference)
//
#include <hip/hip_runtime.h>

#define B_   8
#define CIN  8
#define COUT 32
#define H_   128
#define W_   128
#define OH   126
#define OW   126
#define TW   32
#define TH   8
#define XW   (TW + 4)   // 36 x-cols per tile
#define XH   (TH + 4)   // 12 x-rows per tile
#define YW   (TW + 2)   // 34 y-cols per tile
#define YH   (TH + 2)   // 10 y-rows per tile
#define NTJ  4          // ceil(126/32)
#define NTI  16         // ceil(126/8)

// One block = one 8x32 output tile of one batch image. Three phases:
//  A) stage x[8][12][36] tile into LDS (coalesced, clamped at image edge)
//  B) conv+bias -> ys[8][10][34] in LDS (each y value exact for global-valid
//     rows/cols; garbage only at rows>=OH / cols>=OW, which stage C masks)
//  C) per-thread: tv[8][9] taps from LDS -> registers (NO launch_bounds cap:
//     round-6 showed capping to 64 VGPR spills tv -> 300MB scratch traffic),
//     then min over 32 output channels of masked max over (c,tap).
__global__ __launch_bounds__(256) void fused_kernel(
    const float* __restrict__ x, const float* __restrict__ w,
    const float* __restrict__ bias, float* __restrict__ out) {
  __shared__ float xs[CIN][XH][XW];  // 13824 B
  __shared__ float ys[CIN][YH][YW];  // 10880 B

  int tid = threadIdx.x;
  int blk = blockIdx.x;
  int tj0 = (blk % NTJ) * TW;
  int ti0 = ((blk / NTJ) % NTI) * TH;
  int b   = blk / (NTJ * NTI);

  // ---- Phase A: stage x tile ----
  const float* xb = x + (long)b * CIN * H_ * W_;
  for (int e = tid; e < CIN * XH * XW; e += 256) {
    int cc = e % XW;
    int rr = (e / XW) % XH;
    int ci = e / (XW * XH);
    int gi = ti0 + rr; if (gi > H_ - 1) gi = H_ - 1;  // clamp (masked later)
    int gj = tj0 + cc; if (gj > W_ - 1) gj = W_ - 1;
    xs[ci][rr][cc] = xb[(ci * H_ + gi) * W_ + gj];
  }
  __syncthreads();

  // ---- Phase B: conv + bias into ys ----
  for (int p = tid; p < YH * YW; p += 256) {
    int yr = p / YW;
    int yc = p % YW;
    float acc[CIN];
#pragma unroll
    for (int c = 0; c < CIN; ++c) acc[c] = bias[c];
#pragma unroll
    for (int ci = 0; ci < CIN; ++ci) {
#pragma unroll
      for (int kh = 0; kh < 3; ++kh) {
        float x0 = xs[ci][yr + kh][yc + 0];
        float x1 = xs[ci][yr + kh][yc + 1];
        float x2 = xs[ci][yr + kh][yc + 2];
#pragma unroll
        for (int c = 0; c < CIN; ++c) {
          const float* wp = w + ((c * CIN + ci) * 3 + kh) * 3;  // imm-offset s_load
          acc[c] = fmaf(x2, wp[2], fmaf(x1, wp[1], fmaf(x0, wp[0], acc[c])));
        }
      }
    }
#pragma unroll
    for (int c = 0; c < CIN; ++c) ys[c][yr][yc] = acc[c];
  }
  __syncthreads();

  // ---- Phase C: stage2 on the 8x32 tile, one pixel per thread ----
  int ti = tid >> 5;         // 0..7
  int tj = tid & 31;         // 0..31
  int i = ti0 + ti, j = tj0 + tj;

  float tv[CIN][9];          // stays in VGPRs (static indexing only)
#pragma unroll
  for (int c = 0; c < CIN; ++c) {
#pragma unroll
    for (int kh = 0; kh < 3; ++kh) {
#pragma unroll
      for (int kw = 0; kw < 3; ++kw)
        tv[c][kh * 3 + kw] = ys[c][ti + kh][tj + kw];
    }
  }

  // tap validity from GLOBAL coords (reference pads with -inf)
  bool v1h = (i + 1) < OH, v2h = (i + 2) < OH;
  bool v1w = (j + 1) < OW, v2w = (j + 2) < OW;
  bool vt1 = v1w, vt2 = v2w;
  bool vt3 = v1h, vt4 = v1h && v1w, vt5 = v1h && v2w;
  bool vt6 = v2h, vt7 = v2h && v1w, vt8 = v2h && v2w;

  const float NI = -__builtin_inff();
  float mn = __builtin_inff();

#pragma unroll 4
  for (int o = 0; o < COUT; ++o) {
    const float* wo = w + o * (CIN * 9);   // wave-uniform -> s_load
    float m[9];
#pragma unroll
    for (int k = 0; k < 9; ++k) m[k] = tv[0][k] * wo[k];
#pragma unroll
    for (int c = 1; c < CIN; ++c) {
#pragma unroll
      for (int k = 0; k < 9; ++k)
        m[k] = fmaxf(m[k], tv[c][k] * wo[c * 9 + k]);
    }
    float z1 = vt1 ? m[1] : NI, z2 = vt2 ? m[2] : NI, z3 = vt3 ? m[3] : NI;
    float z4 = vt4 ? m[4] : NI, z5 = vt5 ? m[5] : NI, z6 = vt6 ? m[6] : NI;
    float z7 = vt7 ? m[7] : NI, z8 = vt8 ? m[8] : NI;
    float mx = fmaxf(fmaxf(fmaxf(m[0], z1), fmaxf(z2, z3)),
                     fmaxf(fmaxf(z4, z5), fmaxf(z6, z7)));
    mx = fmaxf(mx, z8);
    mn = fminf(mn, mx);
  }

  if (i < OH && j < OW) out[(b * OH + i) * OW + j] = 2.0f * mn;
}

extern "C" void kernel_launch(void* const* d_in, const int* in_sizes, int n_in,
                              void* d_out, int out_size, void* d_ws, size_t ws_size,
                              hipStream_t stream) {
  const float* x    = (const float*)d_in[0];  // (8,8,128,128)
  const float* w    = (const float*)d_in[1];  // (32,8,3,3)
  const float* bias = (const float*)d_in[2];  // (32,)
  float* out = (float*)d_out;                 // (8,1,126,126) fp32

  const int blocks = B_ * NTI * NTJ;          // 512 tiles
  fused_kernel<<<blocks, 256, 0, stream>>>(x, w, bias, out);
}

// Round 11
// 146.438 us; speedup vs baseline: 2.1131x; 2.1131x over previous
//
#include <hip/hip_runtime.h>

#define B_   8
#define CIN  8
#define COUT 32
#define H_   128
#define W_   128
#define OH   126
#define OW   126
#define TW   32
#define TH   8
#define XW   (TW + 4)   // 36 x-cols per tile
#define XH   (TH + 4)   // 12 x-rows per tile
#define YW   (TW + 2)   // 34 y-cols per tile
#define YH   (TH + 2)   // 10 y-rows per tile
#define NTJ  4          // ceil(126/32)
#define NTI  16         // ceil(126/8)

// One block = one 8x32 output tile. Phases:
//  A) stage x[8][12][36] -> LDS (coalesced, edge-clamped; garbage masked later)
//  B) conv+bias -> ys[8][10][34] in LDS. Per pixel: 72 x-taps -> VGPRs ONCE,
//     then an UNROLL-1 loop over 8 output channels, each s_loading its own 72
//     contiguous weight dwords. Round-9 lesson: fully-unrolled weight loops
//     want 288..576 scalars live -> SGPR overflow -> per-use demoted loads.
//     Unroll-1 with loop-variant s_load addresses keeps the live set at 72.
//  C) stage2: tv[8][9] in VGPRs, UNROLL-1 loop over 32 output channels with a
//     72-dword s_load batch per iteration; 3-ary fmaxf nesting for v_max3.
__global__ __launch_bounds__(256) void fused_kernel(
    const float* __restrict__ x, const float* __restrict__ w,
    const float* __restrict__ bias, float* __restrict__ out) {
  __shared__ float xs[CIN][XH][XW];  // 13824 B
  __shared__ float ys[CIN][YH][YW];  // 10880 B

  int tid = threadIdx.x;
  int blk = blockIdx.x;
  int tj0 = (blk % NTJ) * TW;
  int ti0 = ((blk / NTJ) % NTI) * TH;
  int b   = blk / (NTJ * NTI);

  // ---- Phase A: stage x tile ----
  const float* xb = x + (long)b * CIN * H_ * W_;
  for (int e = tid; e < CIN * XH * XW; e += 256) {
    int cc = e % XW;
    int rr = (e / XW) % XH;
    int ci = e / (XW * XH);
    int gi = ti0 + rr; if (gi > H_ - 1) gi = H_ - 1;  // clamp (masked later)
    int gj = tj0 + cc; if (gj > W_ - 1) gj = W_ - 1;
    xs[ci][rr][cc] = xb[(ci * H_ + gi) * W_ + gj];
  }
  __syncthreads();

  // ---- Phase B: conv + bias into ys ----
#pragma unroll 1
  for (int p = tid; p < YH * YW; p += 256) {
    int yr = p / YW;
    int yc = p % YW;

    // 72 x-taps -> registers (static indexing only)
    float xv[CIN][3][3];
#pragma unroll
    for (int ci = 0; ci < CIN; ++ci)
#pragma unroll
      for (int kh = 0; kh < 3; ++kh)
#pragma unroll
        for (int kw = 0; kw < 3; ++kw)
          xv[ci][kh][kw] = xs[ci][yr + kh][yc + kw];

#pragma unroll 1
    for (int c = 0; c < CIN; ++c) {           // unroll 1: 72 weight dwords live
      const float* wc = w + c * (CIN * 9);    // wave-uniform, varies with c
      float acc = bias[c];
#pragma unroll
      for (int ci = 0; ci < CIN; ++ci)
#pragma unroll
        for (int kh = 0; kh < 3; ++kh)
#pragma unroll
          for (int kw = 0; kw < 3; ++kw)
            acc = fmaf(xv[ci][kh][kw], wc[ci * 9 + kh * 3 + kw], acc);
      ys[c][yr][yc] = acc;
    }
  }
  __syncthreads();

  // ---- Phase C: stage2, one pixel per thread ----
  int ti = tid >> 5;         // 0..7
  int tj = tid & 31;         // 0..31
  int i = ti0 + ti, j = tj0 + tj;

  float tv[CIN][9];
#pragma unroll
  for (int c = 0; c < CIN; ++c)
#pragma unroll
    for (int kh = 0; kh < 3; ++kh)
#pragma unroll
      for (int kw = 0; kw < 3; ++kw)
        tv[c][kh * 3 + kw] = ys[c][ti + kh][tj + kw];

  bool v1h = (i + 1) < OH, v2h = (i + 2) < OH;
  bool v1w = (j + 1) < OW, v2w = (j + 2) < OW;
  bool vt1 = v1w, vt2 = v2w;
  bool vt3 = v1h, vt4 = v1h && v1w, vt5 = v1h && v2w;
  bool vt6 = v2h, vt7 = v2h && v1w, vt8 = v2h && v2w;

  const float NI = -__builtin_inff();
  float mn = __builtin_inff();

#pragma unroll 1
  for (int o = 0; o < COUT; ++o) {            // unroll 1: 72 weight dwords live
    const float* wo = w + o * (CIN * 9);      // wave-uniform, varies with o
    float m[9];
#pragma unroll
    for (int k = 0; k < 9; ++k) {
      float p0 = tv[0][k] * wo[0 * 9 + k];
      float p1 = tv[1][k] * wo[1 * 9 + k];
      float p2 = tv[2][k] * wo[2 * 9 + k];
      float p3 = tv[3][k] * wo[3 * 9 + k];
      float p4 = tv[4][k] * wo[4 * 9 + k];
      float p5 = tv[5][k] * wo[5 * 9 + k];
      float p6 = tv[6][k] * wo[6 * 9 + k];
      float p7 = tv[7][k] * wo[7 * 9 + k];
      float t0 = fmaxf(fmaxf(p0, p1), p2);    // 3-ary -> v_max3
      float t1 = fmaxf(fmaxf(p3, p4), p5);
      float t2 = fmaxf(p6, p7);
      m[k] = fmaxf(fmaxf(t0, t1), t2);
    }
    float z1 = vt1 ? m[1] : NI, z2 = vt2 ? m[2] : NI, z3 = vt3 ? m[3] : NI;
    float z4 = vt4 ? m[4] : NI, z5 = vt5 ? m[5] : NI, z6 = vt6 ? m[6] : NI;
    float z7 = vt7 ? m[7] : NI, z8 = vt8 ? m[8] : NI;
    float u0 = fmaxf(fmaxf(m[0], z1), z2);
    float u1 = fmaxf(fmaxf(z3, z4), z5);
    float u2 = fmaxf(fmaxf(z6, z7), z8);
    float mx = fmaxf(fmaxf(u0, u1), u2);
    mn = fminf(mn, mx);
  }

  if (i < OH && j < OW) out[(b * OH + i) * OW + j] = 2.0f * mn;
}

extern "C" void kernel_launch(void* const* d_in, const int* in_sizes, int n_in,
                              void* d_out, int out_size, void* d_ws, size_t ws_size,
                              hipStream_t stream) {
  const float* x    = (const float*)d_in[0];  // (8,8,128,128)
  const float* w    = (const float*)d_in[1];  // (32,8,3,3)
  const float* bias = (const float*)d_in[2];  // (32,)
  float* out = (float*)d_out;                 // (8,1,126,126) fp32

  const int blocks = B_ * NTI * NTJ;          // 512 tiles
  fused_kernel<<<blocks, 256, 0, stream>>>(x, w, bias, out);
}

// Round 13
// 115.953 us; speedup vs baseline: 2.6687x; 1.2629x over previous
//
#include <hip/hip_runtime.h>

#define B_   8
#define CIN  8
#define COUT 32
#define H_   128
#define W_   128
#define OH   126
#define OW   126
#define TW   32
#define TH   4
#define XW   (TW + 4)   // 36
#define XH   (TH + 4)   // 8
#define YW   (TW + 2)   // 34
#define YH   (TH + 2)   // 6
#define NTJ  4
#define NTI  32         // ceil(126/4) -> rows 124..127 masked
#define NPIXT (TH * TW) // 128 output pixels per block

// Block = 256 threads over a 4x32 output tile; each pixel gets TWO threads
// (half = tid>>7), each covering 16 of the 32 output channels -> 4096 waves
// total = 16 waves/CU = 4 waves/SIMD (matches the VGPR-124 cap; round-11 was
// grid-capped at 2 waves/SIMD). Weights+bias staged to LDS once per block so
// the per-o operand fetch is pipelined ds_read broadcast, not serial SMEM.
__global__ __launch_bounds__(256) void fused_kernel(
    const float* __restrict__ x, const float* __restrict__ w,
    const float* __restrict__ bias, float* __restrict__ out) {
  __shared__ float xs[CIN][XH][XW];   // 9216 B
  __shared__ float ys[CIN][YH][YW];   // 6528 B
  __shared__ float ws[COUT * CIN * 9];// 9216 B
  __shared__ float bs[COUT];          // 128 B
  __shared__ float red[NPIXT];        // 512 B   (total 25600 B)

  int tid = threadIdx.x;
  int blk = blockIdx.x;
  int tj0 = (blk % NTJ) * TW;
  int ti0 = ((blk / NTJ) % NTI) * TH;
  int b   = blk / (NTJ * NTI);

  // ---- Phase A: stage x tile + all weights + bias ----
  const float* xb = x + (long)b * CIN * H_ * W_;
#pragma unroll 1
  for (int e = tid; e < CIN * XH * XW; e += 256) {   // 2304 = 9 passes
    int cc = e % XW;
    int rr = (e / XW) % XH;
    int ci = e / (XW * XH);
    int gi = ti0 + rr; if (gi > H_ - 1) gi = H_ - 1; // clamp (masked later)
    int gj = tj0 + cc; if (gj > W_ - 1) gj = W_ - 1;
    xs[ci][rr][cc] = xb[(ci * H_ + gi) * W_ + gj];
  }
#pragma unroll 1
  for (int e = tid; e < COUT * CIN * 9; e += 256) ws[e] = w[e];  // 2304
  if (tid < COUT) bs[tid] = bias[tid];
  __syncthreads();

  // ---- Phase B: conv + bias -> ys (204 pixels, threads 0..203) ----
  if (tid < YH * YW) {
    int yr = tid / YW;
    int yc = tid % YW;
    float xv[CIN][3][3];
#pragma unroll
    for (int ci = 0; ci < CIN; ++ci)
#pragma unroll
      for (int kh = 0; kh < 3; ++kh)
#pragma unroll
        for (int kw = 0; kw < 3; ++kw)
          xv[ci][kh][kw] = xs[ci][yr + kh][yc + kw];

#pragma unroll 1
    for (int c = 0; c < CIN; ++c) {
      const float* wc = &ws[c * (CIN * 9)];
      float acc = bs[c];
#pragma unroll
      for (int ci = 0; ci < CIN; ++ci)
#pragma unroll
        for (int kh = 0; kh < 3; ++kh)
#pragma unroll
          for (int kw = 0; kw < 3; ++kw)
            acc = fmaf(xv[ci][kh][kw], wc[ci * 9 + kh * 3 + kw], acc);
      ys[c][yr][yc] = acc;
    }
  }
  __syncthreads();

  // ---- Phase C: stage2; 2 threads per pixel, 16 o's each ----
  int pix  = tid & (NPIXT - 1);      // 0..127
  int half = tid >> 7;               // 0 or 1 (wave-uniform: waves 0,1 vs 2,3)
  int ti = pix >> 5;                 // 0..3
  int tj = pix & 31;                 // 0..31
  int i = ti0 + ti, j = tj0 + tj;

  float tv[CIN][9];
#pragma unroll
  for (int c = 0; c < CIN; ++c)
#pragma unroll
    for (int kh = 0; kh < 3; ++kh)
#pragma unroll
      for (int kw = 0; kw < 3; ++kw)
        tv[c][kh * 3 + kw] = ys[c][ti + kh][tj + kw];

  bool v1h = (i + 1) < OH, v2h = (i + 2) < OH;
  bool v1w = (j + 1) < OW, v2w = (j + 2) < OW;
  bool vt1 = v1w, vt2 = v2w;
  bool vt3 = v1h, vt4 = v1h && v1w, vt5 = v1h && v2w;
  bool vt6 = v2h, vt7 = v2h && v1w, vt8 = v2h && v2w;

  const float NI = -__builtin_inff();
  float mn = __builtin_inff();

#pragma unroll 1
  for (int oo = 0; oo < COUT / 2; ++oo) {
    const float* wo = &ws[(half * (COUT / 2) + oo) * (CIN * 9)];
    float m[9];
#pragma unroll
    for (int k = 0; k < 9; ++k) {
      float p0 = tv[0][k] * wo[0 * 9 + k];
      float p1 = tv[1][k] * wo[1 * 9 + k];
      float p2 = tv[2][k] * wo[2 * 9 + k];
      float p3 = tv[3][k] * wo[3 * 9 + k];
      float p4 = tv[4][k] * wo[4 * 9 + k];
      float p5 = tv[5][k] * wo[5 * 9 + k];
      float p6 = tv[6][k] * wo[6 * 9 + k];
      float p7 = tv[7][k] * wo[7 * 9 + k];
      float t0 = fmaxf(fmaxf(p0, p1), p2);   // 3-ary -> v_max3
      float t1 = fmaxf(fmaxf(p3, p4), p5);
      float t2 = fmaxf(p6, p7);
      m[k] = fmaxf(fmaxf(t0, t1), t2);
    }
    float z1 = vt1 ? m[1] : NI, z2 = vt2 ? m[2] : NI, z3 = vt3 ? m[3] : NI;
    float z4 = vt4 ? m[4] : NI, z5 = vt5 ? m[5] : NI, z6 = vt6 ? m[6] : NI;
    float z7 = vt7 ? m[7] : NI, z8 = vt8 ? m[8] : NI;
    float u0 = fmaxf(fmaxf(m[0], z1), z2);
    float u1 = fmaxf(fmaxf(z3, z4), z5);
    float u2 = fmaxf(fmaxf(z6, z7), z8);
    float mx = fmaxf(fmaxf(u0, u1), u2);
    mn = fminf(mn, mx);
  }

  // pairwise min-reduce across the two halves
  if (half == 1) red[pix] = mn;
  __syncthreads();
  if (half == 0) {
    float r = fminf(mn, red[pix]);
    if (i < OH && j < OW) out[(b * OH + i) * OW + j] = 2.0f * r;
  }
}

extern "C" void kernel_launch(void* const* d_in, const int* in_sizes, int n_in,
                              void* d_out, int out_size, void* d_ws, size_t ws_size,
                              hipStream_t stream) {
  const float* x    = (const float*)d_in[0];  // (8,8,128,128)
  const float* w    = (const float*)d_in[1];  // (32,8,3,3)
  const float* bias = (const float*)d_in[2];  // (32,)
  float* out = (float*)d_out;                 // (8,1,126,126) fp32

  const int blocks = B_ * NTI * NTJ;          // 1024 tiles
  fused_kernel<<<blocks, 256, 0, stream>>>(x, w, bias, out);
}